// Round 5
// baseline (45.767 us; speedup 1.0000x reference)
//
#include <hip/hip_runtime.h>

// RBF activation: out[n,c,h,w] = sum_i w[c,i] * exp(-(x - mu_i)^2 / (2 sigma^2))
// x (8,64,256,256) f32, w (1,64,1,1,31) f32, mu (31,) f32, sigma scalar (== tap spacing).
//
// out = f_c(x): fixed smooth per-channel scalar function -> per-block LDS LUT,
// linear interp. LUT stored as single f32 value array A[1025]; hot path is
// ~8 VALU + one ds_read2_b32 (A[j], A[j+1]) per element. 4-byte entries ->
// bank j%32 -> ~2-way aliasing (free), vs 8-byte pairs' 4-way conflicts.
// Grid 2048 blocks, block -> (channel, image, quarter-slab) mapping: channel is
// block-uniform, full 32-wave/CU occupancy, one LUT build per 16 iterations.
// Interp error <= |f''| h^2/8 ~ 1.6e-5 (threshold 1.77e-3).

static constexpr int KW    = 31;    // number of RBF taps
static constexpr int WIN   = 9;     // build window (radius 4; truncation ~3e-6)
static constexpr int RAD   = 4;
static constexpr int LUT_N = 1024;  // LUT intervals (1025 nodes)

typedef float f32x4 __attribute__((ext_vector_type(4)));
typedef float f32x2 __attribute__((ext_vector_type(2)));

// Windowed Gaussian-sum via geometric recurrence (LUT build path).
__device__ __forceinline__ float rbf_win(float xe, const float* __restrict__ wrow,
                                         float mu0, float inv_d, float cd2, float g) {
    const float t = (xe - mu0) * inv_d;             // position in tap units
    float jf = rintf(t) - (float)RAD;               // window start
    jf = fminf(fmaxf(jf, 0.0f), (float)(KW - WIN)); // clamp
    const int s = (int)jf;
    float n = t - jf;
    n = fminf(fmaxf(n, -32.0f), 40.0f);             // keep r0 finite far outside
    float E = __builtin_amdgcn_exp2f(cd2 * n * n);
    float r = __builtin_amdgcn_exp2f(cd2 * fmaf(-2.0f, n, 1.0f));
    float acc = 0.0f;
#pragma unroll
    for (int k = 0; k < WIN; ++k) {
        acc = fmaf(wrow[s + k], E, acc);
        E *= r;
        r *= g;
    }
    return acc;
}

__device__ __forceinline__ void lut_setup(const float* __restrict__ w,
                                          const float* __restrict__ mu,
                                          const float* __restrict__ sigma,
                                          int c, int tid,
                                          float* lutA, float* wrow,
                                          float& invh, float& nlo, float& tmax) {
    const float mu0   = mu[0];
    const float muL   = mu[KW - 1];
    const float dmu   = (muL - mu0) * (1.0f / (KW - 1));
    const float inv_d = 1.0f / dmu;
    const float sg    = sigma[0];
    const float cd2   = -1.4426950408889634f * dmu * dmu / (2.0f * sg * sg);
    const float g     = exp2f(2.0f * cd2);

    // LUT domain: [mu0 - pad, muL + pad], pad = 5.25 sigma (f there ~4e-8).
    const float pad  = 5.25f * sg;
    const float lo   = mu0 - pad;
    const float span = (muL - mu0) + 2.0f * pad;
    const float h    = span * (1.0f / (float)LUT_N);
    invh = (float)LUT_N / span;
    nlo  = -lo * invh;
    tmax = (float)LUT_N - 0.001f;

    if (tid < KW) wrow[tid] = w[c * KW + tid];
    __syncthreads();

    for (int e = tid; e <= LUT_N; e += 256)          // 1025 nodes
        lutA[e] = rbf_win(lo + (float)e * h, wrow, mu0, inv_d, cd2, g);
    __syncthreads();
}

__device__ __forceinline__ float lut_eval(float xe, const float* __restrict__ lutA,
                                          float invh, float nlo, float tmax) {
    float t = fmaf(xe, invh, nlo);
    t = fminf(fmaxf(t, 0.0f), tmax);                 // v_med3
    const int j = (int)t;                            // trunc == floor (t >= 0)
    const float frac = t - (float)j;
    const float a = lutA[j];                         // ds_read2_b32 pair
    const float b = lutA[j + 1];
    return fmaf(frac, b - a, a);
}

// Specialized: N=8, C=64, HW=65536. 2048 blocks; block -> (c, n, quarter).
__global__ __launch_bounds__(256) void rbf_lut_fixed(
    const float* __restrict__ x, const float* __restrict__ w,
    const float* __restrict__ mu, const float* __restrict__ sigma,
    float* __restrict__ out) {
    __shared__ float lutA[LUT_N + 2];
    __shared__ float wrow[32];

    const int tid = threadIdx.x;
    const int c   = blockIdx.x >> 5;                 // 32 blocks per channel
    const int s   = blockIdx.x & 31;
    const int n   = s >> 2;                          // image
    const int q   = s & 3;                           // quarter of the 16384-f4 slab

    // First-chunk prefetch before the LUT build hides HBM latency.
    int i4 = ((n << 6) + c) * 16384 + (q << 12) + tid;
    f32x4 xv = reinterpret_cast<const f32x4*>(x)[i4];

    float invh, nlo, tmax;
    lut_setup(w, mu, sigma, c, tid, lutA, wrow, invh, nlo, tmax);

#pragma unroll
    for (int k = 0; k < 16; ++k) {
        f32x4 xn;
        if (k < 15) xn = reinterpret_cast<const f32x4*>(x)[i4 + 256];
        f32x4 ov;
        ov.x = lut_eval(xv.x, lutA, invh, nlo, tmax);
        ov.y = lut_eval(xv.y, lutA, invh, nlo, tmax);
        ov.z = lut_eval(xv.z, lutA, invh, nlo, tmax);
        ov.w = lut_eval(xv.w, lutA, invh, nlo, tmax);
        __builtin_nontemporal_store(ov, reinterpret_cast<f32x4*>(out) + i4);
        xv = xn;
        i4 += 256;
    }
}

// Generic fallback (any N*C*HW with C=64, HW=65536 layout unknown): R4 scheme.
__global__ __launch_bounds__(256) void rbf_lut_generic(
    const float* __restrict__ x, const float* __restrict__ w,
    const float* __restrict__ mu, const float* __restrict__ sigma,
    float* __restrict__ out, int n4, int ntot, int iters, int c_shift) {
    __shared__ float lutA[LUT_N + 2];
    __shared__ float wrow[32];

    const int tid = threadIdx.x;
    const int gs  = gridDim.x * blockDim.x;
    const int gid = blockIdx.x * blockDim.x + tid;
    const int c   = (gid >> c_shift) & 63;

    float invh, nlo, tmax;
    lut_setup(w, mu, sigma, c, tid, lutA, wrow, invh, nlo, tmax);

    int i4 = gid;
    for (int k = 0; k < iters; ++k) {
        if (i4 < n4) {
            const f32x4 xv = reinterpret_cast<const f32x4*>(x)[i4];
            f32x4 ov;
            ov.x = lut_eval(xv.x, lutA, invh, nlo, tmax);
            ov.y = lut_eval(xv.y, lutA, invh, nlo, tmax);
            ov.z = lut_eval(xv.z, lutA, invh, nlo, tmax);
            ov.w = lut_eval(xv.w, lutA, invh, nlo, tmax);
            __builtin_nontemporal_store(ov, reinterpret_cast<f32x4*>(out) + i4);
        }
        i4 += gs;
    }

    // Scalar tail: exact 31-tap sum.
    const float mu0 = mu[0];
    const float dmu = (mu[KW - 1] - mu0) * (1.0f / (KW - 1));
    const float sg  = sigma[0];
    const float cd2x = -1.4426950408889634f / (2.0f * sg * sg);
    for (int i = n4 * 4 + gid; i < ntot; i += gs) {
        const float xe = x[i];
        const int ct = (i >> (c_shift + 2)) & 63;
        float acc = 0.0f;
        for (int qq = 0; qq < KW; ++qq) {
            const float d = xe - (mu0 + (float)qq * dmu);
            acc = fmaf(w[ct * KW + qq], __builtin_amdgcn_exp2f(cd2x * d * d), acc);
        }
        out[i] = acc;
    }
}

extern "C" void kernel_launch(void* const* d_in, const int* in_sizes, int n_in,
                              void* d_out, int out_size, void* d_ws, size_t ws_size,
                              hipStream_t stream) {
    const float* x  = (const float*)d_in[0];
    const float* w  = (const float*)d_in[1];
    const float* mu = (const float*)d_in[2];
    const float* sg = (const float*)d_in[3];
    float* out = (float*)d_out;

    if (out_size == 8 * 64 * 65536) {
        rbf_lut_fixed<<<2048, 256, 0, stream>>>(x, w, mu, sg, out);
    } else {
        const int n4     = out_size >> 2;
        const int blocks = 4096;
        const int gsz    = blocks * 256;
        const int iters  = (n4 + gsz - 1) / gsz;
        rbf_lut_generic<<<blocks, 256, 0, stream>>>(x, w, mu, sg, out, n4, out_size,
                                                    iters, 14);
    }
}

// Round 6
// 45.720 us; speedup vs baseline: 1.0010x; 1.0010x over previous
//
#include <hip/hip_runtime.h>

// RBF activation: out[n,c,h,w] = sum_i w[c,i] * exp(-(x - mu_i)^2 / (2 sigma^2))
// x (8,64,256,256) f32, w (1,64,1,1,31) f32, mu (31,) f32, sigma scalar (== tap spacing).
//
// out = f_c(x): fixed smooth per-channel scalar function -> per-block LDS LUT,
// linear interp. LUT = 1024 (value, delta) f32 pairs -> hot path is ~6 VALU +
// ONE ds_read_b64 random gather per element (measured best: R4 2.3M conflict
// cycles vs 4.6M for two b32 gathers in R5).
// Build: pass1 1025 node values into scratch, pass2 pairs (halves build evals).
// Grid 4096 blocks: per-iter stride = exactly one image -> thread channel
// constant; channel is block-uniform. Interp error ~1.6e-5 (threshold 1.77e-3).

static constexpr int KW    = 31;    // number of RBF taps
static constexpr int WIN   = 9;     // build window (radius 4; truncation ~3e-6)
static constexpr int RAD   = 4;
static constexpr int LUT_N = 1024;  // LUT intervals (1025 nodes)

typedef float f32x4 __attribute__((ext_vector_type(4)));
typedef float f32x2 __attribute__((ext_vector_type(2)));

// Windowed Gaussian-sum via geometric recurrence (LUT build path).
__device__ __forceinline__ float rbf_win(float xe, const float* __restrict__ wrow,
                                         float mu0, float inv_d, float cd2, float g) {
    const float t = (xe - mu0) * inv_d;             // position in tap units
    float jf = rintf(t) - (float)RAD;               // window start
    jf = fminf(fmaxf(jf, 0.0f), (float)(KW - WIN)); // clamp
    const int s = (int)jf;
    float n = t - jf;
    n = fminf(fmaxf(n, -32.0f), 40.0f);             // keep r0 finite far outside
    float E = __builtin_amdgcn_exp2f(cd2 * n * n);
    float r = __builtin_amdgcn_exp2f(cd2 * fmaf(-2.0f, n, 1.0f));
    float acc = 0.0f;
#pragma unroll
    for (int k = 0; k < WIN; ++k) {
        acc = fmaf(wrow[s + k], E, acc);
        E *= r;
        r *= g;
    }
    return acc;
}

// Build the (value, delta) pair LUT for block-uniform channel c.
__device__ __forceinline__ void lut_setup(const float* __restrict__ w,
                                          const float* __restrict__ mu,
                                          const float* __restrict__ sigma,
                                          int c, int tid,
                                          f32x2* lutP, float* vals, float* wrow,
                                          float& invh, float& nlo, float& tmax) {
    const float mu0   = mu[0];
    const float muL   = mu[KW - 1];
    const float dmu   = (muL - mu0) * (1.0f / (KW - 1));
    const float inv_d = 1.0f / dmu;
    const float sg    = sigma[0];
    const float cd2   = -1.4426950408889634f * dmu * dmu / (2.0f * sg * sg);
    const float g     = exp2f(2.0f * cd2);

    // LUT domain: [mu0 - pad, muL + pad], pad = 5.25 sigma (f there ~4e-8).
    const float pad  = 5.25f * sg;
    const float lo   = mu0 - pad;
    const float span = (muL - mu0) + 2.0f * pad;
    const float h    = span * (1.0f / (float)LUT_N);
    invh = (float)LUT_N / span;
    nlo  = -lo * invh;
    tmax = (float)LUT_N - 0.001f;

    if (tid < KW) wrow[tid] = w[c * KW + tid];
    __syncthreads();

    // Pass 1: 1025 node values (4-5 windowed evals per thread).
    for (int e = tid; e <= LUT_N; e += 256)
        vals[e] = rbf_win(lo + (float)e * h, wrow, mu0, inv_d, cd2, g);
    __syncthreads();

    // Pass 2: pairs (stride-1 b32 reads: 2-way aliasing, free).
    for (int e = tid; e < LUT_N; e += 256) {
        f32x2 p; p.x = vals[e]; p.y = vals[e + 1] - vals[e];
        lutP[e] = p;
    }
    __syncthreads();
}

__device__ __forceinline__ float lut_eval(float xe, const f32x2* __restrict__ lutP,
                                          float invh, float nlo, float tmax) {
    float t = fmaf(xe, invh, nlo);
    t = fminf(fmaxf(t, 0.0f), tmax);                 // v_med3
    const int j = (int)t;                            // trunc == floor (t >= 0)
    const float frac = t - (float)j;
    const f32x2 ab = lutP[j];                        // one ds_read_b64 gather
    return fmaf(frac, ab.y, ab.x);
}

// Specialized: N=8, C=64, HW=65536; 4096 blocks x 8 fully-unrolled iterations.
// Per-iter stride 4096*256 f4 = 1,048,576 f4 = one image -> channel constant.
__global__ __launch_bounds__(256) void rbf_lut_fixed(
    const float* __restrict__ x, const float* __restrict__ w,
    const float* __restrict__ mu, const float* __restrict__ sigma,
    float* __restrict__ out) {
    __shared__ f32x2 lutP[LUT_N];
    __shared__ float vals[LUT_N + 1];
    __shared__ float wrow[32];

    const int tid = threadIdx.x;
    const int gid = blockIdx.x * 256 + tid;
    const int c   = (gid >> 14) & 63;                // 16384 f4 per channel row

    // First-chunk prefetch before the LUT build hides HBM latency.
    int i4 = gid;
    f32x4 xv = reinterpret_cast<const f32x4*>(x)[i4];

    float invh, nlo, tmax;
    lut_setup(w, mu, sigma, c, tid, lutP, vals, wrow, invh, nlo, tmax);

#pragma unroll
    for (int k = 0; k < 8; ++k) {
        f32x4 xn;
        if (k < 7) xn = reinterpret_cast<const f32x4*>(x)[i4 + (1 << 20)];
        f32x4 ov;
        ov.x = lut_eval(xv.x, lutP, invh, nlo, tmax);
        ov.y = lut_eval(xv.y, lutP, invh, nlo, tmax);
        ov.z = lut_eval(xv.z, lutP, invh, nlo, tmax);
        ov.w = lut_eval(xv.w, lutP, invh, nlo, tmax);
        __builtin_nontemporal_store(ov, reinterpret_cast<f32x4*>(out) + i4);
        xv = xn;
        i4 += (1 << 20);                             // one image of float4s
    }
}

// Generic fallback for other shapes (C=64 rows of 65536 assumed via c_shift).
__global__ __launch_bounds__(256) void rbf_lut_generic(
    const float* __restrict__ x, const float* __restrict__ w,
    const float* __restrict__ mu, const float* __restrict__ sigma,
    float* __restrict__ out, int n4, int ntot, int iters, int c_shift) {
    __shared__ f32x2 lutP[LUT_N];
    __shared__ float vals[LUT_N + 1];
    __shared__ float wrow[32];

    const int tid = threadIdx.x;
    const int gs  = gridDim.x * blockDim.x;
    const int gid = blockIdx.x * blockDim.x + tid;
    const int c   = (gid >> c_shift) & 63;

    float invh, nlo, tmax;
    lut_setup(w, mu, sigma, c, tid, lutP, vals, wrow, invh, nlo, tmax);

    int i4 = gid;
    for (int k = 0; k < iters; ++k) {
        if (i4 < n4) {
            const f32x4 xv = reinterpret_cast<const f32x4*>(x)[i4];
            f32x4 ov;
            ov.x = lut_eval(xv.x, lutP, invh, nlo, tmax);
            ov.y = lut_eval(xv.y, lutP, invh, nlo, tmax);
            ov.z = lut_eval(xv.z, lutP, invh, nlo, tmax);
            ov.w = lut_eval(xv.w, lutP, invh, nlo, tmax);
            __builtin_nontemporal_store(ov, reinterpret_cast<f32x4*>(out) + i4);
        }
        i4 += gs;
    }

    // Scalar tail: exact 31-tap sum.
    const float mu0 = mu[0];
    const float dmu = (mu[KW - 1] - mu0) * (1.0f / (KW - 1));
    const float sg  = sigma[0];
    const float cd2x = -1.4426950408889634f / (2.0f * sg * sg);
    for (int i = n4 * 4 + gid; i < ntot; i += gs) {
        const float xe = x[i];
        const int ct = (i >> (c_shift + 2)) & 63;
        float acc = 0.0f;
        for (int qq = 0; qq < KW; ++qq) {
            const float d = xe - (mu0 + (float)qq * dmu);
            acc = fmaf(w[ct * KW + qq], __builtin_amdgcn_exp2f(cd2x * d * d), acc);
        }
        out[i] = acc;
    }
}

extern "C" void kernel_launch(void* const* d_in, const int* in_sizes, int n_in,
                              void* d_out, int out_size, void* d_ws, size_t ws_size,
                              hipStream_t stream) {
    const float* x  = (const float*)d_in[0];
    const float* w  = (const float*)d_in[1];
    const float* mu = (const float*)d_in[2];
    const float* sg = (const float*)d_in[3];
    float* out = (float*)d_out;

    if (out_size == 8 * 64 * 65536) {
        rbf_lut_fixed<<<4096, 256, 0, stream>>>(x, w, mu, sg, out);
    } else {
        const int n4     = out_size >> 2;
        const int blocks = 4096;
        const int gsz    = blocks * 256;
        const int iters  = (n4 + gsz - 1) / gsz;
        rbf_lut_generic<<<blocks, 256, 0, stream>>>(x, w, mu, sg, out, n4, out_size,
                                                    iters, 14);
    }
}

// Round 7
// 45.430 us; speedup vs baseline: 1.0074x; 1.0064x over previous
//
#include <hip/hip_runtime.h>

// RBF activation: out[n,c,h,w] = sum_i w[c,i] * exp(-(x - mu_i)^2 / (2 sigma^2))
// x (8,64,256,256) f32, w (1,64,1,1,31) f32, mu (31,) f32, sigma scalar (== tap spacing).
//
// out = f_c(x): per-block LDS LUT (1024 x (value,delta) f32 pairs), linear interp.
// Hot path: ~6 VALU + ONE ds_read_b64 gather per element (measured best vs 2x b32).
// 2048 blocks = 8/CU exactly (one generation -> one LUT build per block, amortized
// over 16 contiguous chunks); block -> (channel, image, quarter-slab) mapping keeps
// channel block-uniform. 2-deep prefetch for 2 outstanding loads/wave.
// Interp error ~1.6e-5; window truncation ~3e-6 (threshold 1.77e-3).

static constexpr int KW    = 31;    // number of RBF taps
static constexpr int WIN   = 9;     // build window (radius 4)
static constexpr int RAD   = 4;
static constexpr int LUT_N = 1024;  // LUT intervals (1025 nodes)

typedef float f32x4 __attribute__((ext_vector_type(4)));
typedef float f32x2 __attribute__((ext_vector_type(2)));

// Windowed Gaussian-sum via geometric recurrence (LUT build path).
__device__ __forceinline__ float rbf_win(float xe, const float* __restrict__ wrow,
                                         float mu0, float inv_d, float cd2, float g) {
    const float t = (xe - mu0) * inv_d;             // position in tap units
    float jf = rintf(t) - (float)RAD;               // window start
    jf = fminf(fmaxf(jf, 0.0f), (float)(KW - WIN)); // clamp
    const int s = (int)jf;
    float n = t - jf;
    n = fminf(fmaxf(n, -32.0f), 40.0f);             // keep r0 finite far outside
    float E = __builtin_amdgcn_exp2f(cd2 * n * n);
    float r = __builtin_amdgcn_exp2f(cd2 * fmaf(-2.0f, n, 1.0f));
    float acc = 0.0f;
#pragma unroll
    for (int k = 0; k < WIN; ++k) {
        acc = fmaf(wrow[s + k], E, acc);
        E *= r;
        r *= g;
    }
    return acc;
}

// Build the (value, delta) pair LUT for block-uniform channel c.
__device__ __forceinline__ void lut_setup(const float* __restrict__ w,
                                          const float* __restrict__ mu,
                                          const float* __restrict__ sigma,
                                          int c, int tid,
                                          f32x2* lutP, float* vals, float* wrow,
                                          float& invh, float& nlo, float& tmax) {
    const float mu0   = mu[0];
    const float muL   = mu[KW - 1];
    const float dmu   = (muL - mu0) * (1.0f / (KW - 1));
    const float inv_d = 1.0f / dmu;
    const float sg    = sigma[0];
    const float cd2   = -1.4426950408889634f * dmu * dmu / (2.0f * sg * sg);
    const float g     = exp2f(2.0f * cd2);

    // LUT domain: [mu0 - pad, muL + pad], pad = 5.25 sigma (f there ~4e-8).
    const float pad  = 5.25f * sg;
    const float lo   = mu0 - pad;
    const float span = (muL - mu0) + 2.0f * pad;
    const float h    = span * (1.0f / (float)LUT_N);
    invh = (float)LUT_N / span;
    nlo  = -lo * invh;
    tmax = (float)LUT_N - 0.001f;

    if (tid < KW) wrow[tid] = w[c * KW + tid];
    __syncthreads();

    // Pass 1: 1025 node values (4-5 windowed evals per thread).
    for (int e = tid; e <= LUT_N; e += 256)
        vals[e] = rbf_win(lo + (float)e * h, wrow, mu0, inv_d, cd2, g);
    __syncthreads();

    // Pass 2: (value, delta) pairs; stride-1 b32 reads (2-way aliasing, free).
    for (int e = tid; e < LUT_N; e += 256) {
        f32x2 p; p.x = vals[e]; p.y = vals[e + 1] - vals[e];
        lutP[e] = p;
    }
    __syncthreads();
}

__device__ __forceinline__ float lut_eval(float xe, const f32x2* __restrict__ lutP,
                                          float invh, float nlo, float tmax) {
    float t = fmaf(xe, invh, nlo);
    t = fminf(fmaxf(t, 0.0f), tmax);                 // v_med3
    const int j = (int)t;                            // trunc == floor (t >= 0)
    const float frac = t - (float)j;
    const f32x2 ab = lutP[j];                        // one ds_read_b64 gather
    return fmaf(frac, ab.y, ab.x);
}

// Specialized: N=8, C=64, HW=65536. 2048 blocks (8/CU, one generation).
// block -> (c, n, q); each block streams 16 contiguous 256-f4 chunks (64KB)
// of one channel row. 2-deep prefetch.
__global__ __launch_bounds__(256) void rbf_lut_fixed(
    const float* __restrict__ x, const float* __restrict__ w,
    const float* __restrict__ mu, const float* __restrict__ sigma,
    float* __restrict__ out) {
    __shared__ f32x2 lutP[LUT_N];
    __shared__ float vals[LUT_N + 1];
    __shared__ float wrow[32];

    const int tid = threadIdx.x;
    const int c   = blockIdx.x >> 5;                 // 32 blocks per channel
    const int s   = blockIdx.x & 31;
    const int n   = s >> 2;                          // image
    const int q   = s & 3;                           // quarter of 16384-f4 row

    int i4 = ((n << 6) + c) * 16384 + (q << 12) + tid;

    // 2-deep prefetch issued before the LUT build hides HBM latency.
    f32x4 cur = reinterpret_cast<const f32x4*>(x)[i4];
    f32x4 nx1 = reinterpret_cast<const f32x4*>(x)[i4 + 256];

    float invh, nlo, tmax;
    lut_setup(w, mu, sigma, c, tid, lutP, vals, wrow, invh, nlo, tmax);

#pragma unroll
    for (int k = 0; k < 16; ++k) {
        f32x4 nx2;
        if (k < 14) nx2 = reinterpret_cast<const f32x4*>(x)[i4 + 512];
        f32x4 ov;
        ov.x = lut_eval(cur.x, lutP, invh, nlo, tmax);
        ov.y = lut_eval(cur.y, lutP, invh, nlo, tmax);
        ov.z = lut_eval(cur.z, lutP, invh, nlo, tmax);
        ov.w = lut_eval(cur.w, lutP, invh, nlo, tmax);
        __builtin_nontemporal_store(ov, reinterpret_cast<f32x4*>(out) + i4);
        cur = nx1; nx1 = nx2;
        i4 += 256;
    }
}

// Generic fallback for other shapes (assumes C=64 rows of 65536 via c_shift).
__global__ __launch_bounds__(256) void rbf_lut_generic(
    const float* __restrict__ x, const float* __restrict__ w,
    const float* __restrict__ mu, const float* __restrict__ sigma,
    float* __restrict__ out, int n4, int ntot, int iters, int c_shift) {
    __shared__ f32x2 lutP[LUT_N];
    __shared__ float vals[LUT_N + 1];
    __shared__ float wrow[32];

    const int tid = threadIdx.x;
    const int gs  = gridDim.x * blockDim.x;
    const int gid = blockIdx.x * blockDim.x + tid;
    const int c   = (gid >> c_shift) & 63;

    float invh, nlo, tmax;
    lut_setup(w, mu, sigma, c, tid, lutP, vals, wrow, invh, nlo, tmax);

    int i4 = gid;
    for (int k = 0; k < iters; ++k) {
        if (i4 < n4) {
            const f32x4 xv = reinterpret_cast<const f32x4*>(x)[i4];
            f32x4 ov;
            ov.x = lut_eval(xv.x, lutP, invh, nlo, tmax);
            ov.y = lut_eval(xv.y, lutP, invh, nlo, tmax);
            ov.z = lut_eval(xv.z, lutP, invh, nlo, tmax);
            ov.w = lut_eval(xv.w, lutP, invh, nlo, tmax);
            __builtin_nontemporal_store(ov, reinterpret_cast<f32x4*>(out) + i4);
        }
        i4 += gs;
    }

    // Scalar tail: exact 31-tap sum.
    const float mu0 = mu[0];
    const float dmu = (mu[KW - 1] - mu0) * (1.0f / (KW - 1));
    const float sg  = sigma[0];
    const float cd2x = -1.4426950408889634f / (2.0f * sg * sg);
    for (int i = n4 * 4 + gid; i < ntot; i += gs) {
        const float xe = x[i];
        const int ct = (i >> (c_shift + 2)) & 63;
        float acc = 0.0f;
        for (int qq = 0; qq < KW; ++qq) {
            const float d = xe - (mu0 + (float)qq * dmu);
            acc = fmaf(w[ct * KW + qq], __builtin_amdgcn_exp2f(cd2x * d * d), acc);
        }
        out[i] = acc;
    }
}

extern "C" void kernel_launch(void* const* d_in, const int* in_sizes, int n_in,
                              void* d_out, int out_size, void* d_ws, size_t ws_size,
                              hipStream_t stream) {
    const float* x  = (const float*)d_in[0];
    const float* w  = (const float*)d_in[1];
    const float* mu = (const float*)d_in[2];
    const float* sg = (const float*)d_in[3];
    float* out = (float*)d_out;

    if (out_size == 8 * 64 * 65536) {
        rbf_lut_fixed<<<2048, 256, 0, stream>>>(x, w, mu, sg, out);
    } else {
        const int n4     = out_size >> 2;
        const int blocks = 4096;
        const int gsz    = blocks * 256;
        const int iters  = (n4 + gsz - 1) / gsz;
        rbf_lut_generic<<<blocks, 256, 0, stream>>>(x, w, mu, sg, out, n4, out_size,
                                                    iters, 14);
    }
}